// Round 3
// baseline (174.210 us; speedup 1.0000x reference)
//
#include <hip/hip_runtime.h>
#include <hip/hip_bf16.h>

// N=16, M=2, T=300, V=25, C=64, KT=9, PAD=4. NM=32, skeletons SK=9600, rows=240000.
// prep -> gcn (barrier-free, weight frags in regs, 8 KB LDS/wave, y ws [nm][v][t][c])
//      -> conv (1-wave blocks, bf16 MFMA GEMM K=576, swizzled LDS, BN+ReLU+residual).
//
// Workspace: Y (30.72 MB) | WC2 (73.7 KB) | WGT (8 KB) | A2P (2 KB) | SC/SH (256 B each)

typedef __bf16 bf16x8 __attribute__((ext_vector_type(8)));
typedef __bf16 bf16x4 __attribute__((ext_vector_type(4)));
typedef float  f32x4  __attribute__((ext_vector_type(4)));

#define Y_OFF   0
#define WC2_OFF 30720000
#define WGT_OFF 30793728
#define A2P_OFF 30801920
#define SC_OFF  30803968
#define SH_OFF  30804224

__global__ __launch_bounds__(256) void prep_kernel(
    const float* __restrict__ adj, const float* __restrict__ gcn_w,
    const float* __restrict__ conv_w, const float* __restrict__ conv_b,
    const float* __restrict__ bn_g, const float* __restrict__ bn_b,
    const float* __restrict__ bn_m, const float* __restrict__ bn_v,
    __bf16* __restrict__ wc2, __bf16* __restrict__ wgt,
    __bf16* __restrict__ a2p, float* __restrict__ scale, float* __restrict__ shift) {
  int tid = threadIdx.x;
  // conv weights -> fragment layout: wc2[((kk*4+quad)*64 + c)*8 + j] = w[c][ci][kt],
  // kap = (kk*4+quad)*8 + j = kt*64 + ci (kt-major K index).
  for (int e = blockIdx.x * 256 + tid; e < 36864; e += gridDim.x * 256) {
    int j = e & 7, t1 = e >> 3, c = t1 & 63, g = t1 >> 6;
    int kap = g * 8 + j, kt = kap >> 6, ci = kap & 63;
    wc2[e] = (__bf16)conv_w[(c * 64 + ci) * 9 + kt];
  }
  if (blockIdx.x == 0) {
    for (int e = tid; e < 4096; e += 256) {           // wgt[c][k] = gcn_w[k][c]
      int c = e >> 6, k = e & 63;
      wgt[e] = (__bf16)gcn_w[k * 64 + c];
    }
  } else if (blockIdx.x == 1) {
    for (int e = tid; e < 1024; e += 256) {           // A'' 32x32 zero-padded
      int v = e >> 5, u = e & 31;
      float val = 0.f;
      if (v < 25 && u < 25) {
        float dv = 0.f, du = 0.f;
        for (int t = 0; t < 25; ++t) { dv += adj[v * 25 + t]; du += adj[u * 25 + t]; }
        val = rsqrtf(dv) * adj[v * 25 + u] * rsqrtf(du);
      }
      a2p[e] = (__bf16)val;
    }
  } else if (blockIdx.x == 2) {
    if (tid < 64) {
      float sc = bn_g[tid] * rsqrtf(bn_v[tid] + 1e-5f);
      scale[tid] = sc;
      shift[tid] = (conv_b[tid] - bn_m[tid]) * sc + bn_b[tid];
    }
  }
}

// GCN v3: barrier-free, 4 waves/block, 8 KB LDS/wave (32 KB/block -> 5 blocks/CU).
// Weight fragments (Wg^T A-frags, A'' B-frags) live in registers, loaded from L2-hot
// global. X1T = Wg^T . h^T (MFMA), x1t LDS round-trip, yT = X1T . A''^T, ReLU+bias,
// ystage (reuse hb) -> coalesced stores to y[nm][v][t][c].
__global__ __launch_bounds__(256, 4) void gcn_kernel(
    const float* __restrict__ h, const __bf16* __restrict__ wgt_g,
    const __bf16* __restrict__ a2p_g, const float* __restrict__ gcn_b,
    __bf16* __restrict__ y) {
  __shared__ __align__(16) __bf16 hb[4][2048];        // [u=32][k=64], chunk^(u&7) swizzle
  __shared__ __align__(16) __bf16 x1t[4][2048];       // [c=64][u=32] plain (bank-uniform b128)
  int tid = threadIdx.x, w = tid >> 6, lane = tid & 63;
  int l15 = lane & 15, quad = lane >> 4;
  int skel = blockIdx.x * 4 + w;                      // 2400*4 = 9600, all valid
  int nm = skel / 300, tloc = skel - nm * 300;

  // weight fragments from global (same addresses every wave -> L2-hot)
  bf16x8 awg[4][2];
  for (int mt = 0; mt < 4; ++mt)
    for (int kk = 0; kk < 2; ++kk)
      awg[mt][kk] = *(const bf16x8*)&wgt_g[(mt * 16 + l15) * 64 + kk * 32 + quad * 8];
  bf16x8 ba[2];
  for (int nt = 0; nt < 2; ++nt)
    ba[nt] = *(const bf16x8*)&a2p_g[(nt * 16 + l15) * 32 + quad * 8];

  // stage h rows 0..24 (fp32 -> bf16, swizzled), zero rows 25..31 (one b128 instr)
  if (lane < 56) *(uint4*)&hb[w][1600 + lane * 8] = (uint4){0u, 0u, 0u, 0u};
  for (int it = 0; it < 7; ++it) {
    int u = it * 4 + quad;
    if (u < 25) {
      float4 hv = *(const float4*)&h[(skel * 25 + u) * 64 + l15 * 4];
      bf16x4 b4; b4[0] = (__bf16)hv.x; b4[1] = (__bf16)hv.y; b4[2] = (__bf16)hv.z; b4[3] = (__bf16)hv.w;
      int ch = l15 >> 1;
      *(bf16x4*)&hb[w][u * 64 + (((ch ^ (u & 7)) * 8) | ((l15 & 1) * 4))] = b4;
    }
  }
  // GEMM1: M=c(64), N=u(32 pad), K=64
  for (int mt = 0; mt < 4; ++mt)
    for (int nt = 0; nt < 2; ++nt) {
      f32x4 acc = {0.f, 0.f, 0.f, 0.f};
      int u = nt * 16 + l15;
      for (int kk = 0; kk < 2; ++kk) {
        bf16x8 b = *(const bf16x8*)&hb[w][u * 64 + (((kk * 4 + quad) ^ (u & 7)) * 8)];
        acc = __builtin_amdgcn_mfma_f32_16x16x32_bf16(awg[mt][kk], b, acc, 0, 0, 0);
      }
      int c0 = mt * 16 + quad * 4;
      for (int r = 0; r < 4; ++r) x1t[w][(c0 + r) * 32 + u] = (__bf16)acc[r];
    }
  // GEMM2: M=c(64), N=v(32 pad), K=u(32 pad); epilogue -> ystage (reuse hb, swizzled)
  for (int mt = 0; mt < 4; ++mt)
    for (int nt = 0; nt < 2; ++nt) {
      f32x4 acc = {0.f, 0.f, 0.f, 0.f};
      bf16x8 a = *(const bf16x8*)&x1t[w][(mt * 16 + l15) * 32 + quad * 8];
      acc = __builtin_amdgcn_mfma_f32_16x16x32_bf16(a, ba[nt], acc, 0, 0, 0);
      int v = nt * 16 + l15, c0 = mt * 16 + quad * 4;
      if (v < 25) {
        float4 bias = *(const float4*)&gcn_b[c0];
        bf16x4 o;
        o[0] = (__bf16)fmaxf(acc[0] + bias.x, 0.f);
        o[1] = (__bf16)fmaxf(acc[1] + bias.y, 0.f);
        o[2] = (__bf16)fmaxf(acc[2] + bias.z, 0.f);
        o[3] = (__bf16)fmaxf(acc[3] + bias.w, 0.f);
        int ch = (c0 >> 3) ^ (v & 7);
        *(bf16x4*)&hb[w][v * 64 + ((ch * 8) | (c0 & 7))] = o;
      }
    }
  // coalesced store: y[((nm*25+v)*300 + tloc)*64 + c], 25 rows x 128 B
  for (int e = lane; e < 200; e += 64) {
    int v = e >> 3, ch = e & 7;
    uint4 val = *(const uint4*)&hb[w][v * 64 + ((ch ^ (v & 7)) * 8)];
    *(uint4*)&y[((nm * 25 + v) * 300 + tloc) * 64 + ch * 8] = val;
  }
}

// Conv GEMM: 1-wave blocks (64 thr), 64c x 64t tile per wave, K=576. Wave-private
// swizzled LDS y tile, A-frag double-buffer. Epilogue: BN-fold + ReLU + fp32 residual.
__global__ __launch_bounds__(64, 4) void conv_kernel(
    const __bf16* __restrict__ y, const __bf16* __restrict__ wc2,
    const float* __restrict__ scale, const float* __restrict__ shift,
    const float* __restrict__ h, float* __restrict__ out) {
  __shared__ __align__(16) __bf16 my[72 * 64];        // 72 rows x 64c, XOR-swizzled
  int lane = threadIdx.x;
  int l15 = lane & 15, quad = lane >> 4;
  int gid = blockIdx.x;                               // 4000 blocks, all identical work
  int ti = gid % 5, r1 = gid / 5;
  int vv = r1 % 25, nm = r1 / 25;
  int t0 = (ti < 4) ? ti * 64 : 236;                  // last tile overlaps 20 rows (benign)

  { // stage 72 rows x 128 B contiguous from y[nm][vv][t0-4 .. t0+67][:]
    const __bf16* ybase = &y[((nm * 25 + vv) * 300) * 64];
    uint4 stg[9];
    for (int it = 0; it < 9; ++it) {
      int idx = it * 64 + lane, r = idx >> 3, ch = idx & 7;
      int tg = t0 - 4 + r;
      uint4 val = {0u, 0u, 0u, 0u};
      if (tg >= 0 && tg < 300) val = *(const uint4*)&ybase[tg * 64 + ch * 8];
      stg[it] = val;
    }
    for (int it = 0; it < 9; ++it) {
      int idx = it * 64 + lane, r = idx >> 3, ch = idx & 7;
      *(uint4*)&my[r * 64 + ((ch ^ (r & 7)) * 8)] = stg[it];
    }
  }
  // no barriers: LDS tile is wave-private

  f32x4 acc[4][4];
  for (int m = 0; m < 4; ++m) for (int n = 0; n < 4; ++n) acc[m][n] = (f32x4){0.f, 0.f, 0.f, 0.f};

  bf16x8 a0[4], a1[4];
#define LOADA(dst, kk_) { const __bf16* wb = wc2 + (((kk_) * 4 + quad) * 64) * 8; \
    for (int m = 0; m < 4; ++m) dst[m] = *(const bf16x8*)&wb[(m * 16 + l15) * 8]; }
#define COMPUTE(kk_, areg) { int kt = (kk_) >> 1, chb = ((kk_) & 1) * 4 + quad; \
    for (int n = 0; n < 4; ++n) { \
      int row = n * 16 + l15 + kt; \
      bf16x8 b = *(const bf16x8*)&my[row * 64 + ((chb ^ (row & 7)) * 8)]; \
      for (int m = 0; m < 4; ++m) \
        acc[m][n] = __builtin_amdgcn_mfma_f32_16x16x32_bf16(areg[m], b, acc[m][n], 0, 0, 0); \
    } }
  LOADA(a0, 0)
  for (int kk = 0; kk < 18; kk += 2) {
    LOADA(a1, kk + 1)
    COMPUTE(kk, a0)
    if (kk + 2 < 18) LOADA(a0, kk + 2)
    COMPUTE(kk + 1, a1)
  }
#undef LOADA
#undef COMPUTE

  for (int n = 0; n < 4; ++n) {
    int tt = t0 + n * 16 + l15;                       // always < 300 by tile choice
    for (int m = 0; m < 4; ++m) {
      int c0 = m * 16 + quad * 4;
      int idx = ((nm * 300 + tt) * 25 + vv) * 64 + c0;
      float4 sc = *(const float4*)&scale[c0];
      float4 sh = *(const float4*)&shift[c0];
      float4 hr = *(const float4*)&h[idx];
      float4 o;
      o.x = fmaxf(acc[m][n][0] * sc.x + sh.x, 0.f) + hr.x;
      o.y = fmaxf(acc[m][n][1] * sc.y + sh.y, 0.f) + hr.y;
      o.z = fmaxf(acc[m][n][2] * sc.z + sh.z, 0.f) + hr.z;
      o.w = fmaxf(acc[m][n][3] * sc.w + sh.w, 0.f) + hr.w;
      *(float4*)&out[idx] = o;
    }
  }
}

extern "C" void kernel_launch(void* const* d_in, const int* in_sizes, int n_in,
                              void* d_out, int out_size, void* d_ws, size_t ws_size,
                              hipStream_t stream) {
  const float* h      = (const float*)d_in[0];
  const float* adj    = (const float*)d_in[1];
  const float* gcn_w  = (const float*)d_in[2];
  const float* gcn_b  = (const float*)d_in[3];
  const float* conv_w = (const float*)d_in[4];
  const float* conv_b = (const float*)d_in[5];
  const float* bn_g   = (const float*)d_in[6];
  const float* bn_b   = (const float*)d_in[7];
  const float* bn_m   = (const float*)d_in[8];
  const float* bn_v   = (const float*)d_in[9];
  float* out = (float*)d_out;
  char* ws = (char*)d_ws;

  __bf16* y_ws   = (__bf16*)(ws + Y_OFF);
  __bf16* wc2    = (__bf16*)(ws + WC2_OFF);
  __bf16* wgt    = (__bf16*)(ws + WGT_OFF);
  __bf16* a2p    = (__bf16*)(ws + A2P_OFF);
  float*  scale  = (float*)(ws + SC_OFF);
  float*  shift  = (float*)(ws + SH_OFF);

  prep_kernel<<<64, 256, 0, stream>>>(adj, gcn_w, conv_w, conv_b, bn_g, bn_b, bn_m, bn_v,
                                      wc2, wgt, a2p, scale, shift);
  gcn_kernel<<<2400, 256, 0, stream>>>(h, wgt, a2p, gcn_b, y_ws);
  conv_kernel<<<4000, 64, 0, stream>>>(y_ws, wc2, scale, shift, h, out);
}

// Round 4
// 170.014 us; speedup vs baseline: 1.0247x; 1.0247x over previous
//
#include <hip/hip_runtime.h>
#include <hip/hip_bf16.h>

// N=16, M=2, T=300, V=25, C=64, KT=9, PAD=4. NM=32, skeletons SK=9600, rows=240000.
// prep -> gcn (1-wave blocks, reg weight frags, 9.2 KB LDS/wave, y ws [nm][v][t][c])
//      -> conv (4-wave blocks, c-split 16c/wave, shared 72x64 swizzled tile, K=576,
//               BN+ReLU+residual epilogue).
//
// Workspace: Y (30.72 MB) | WC2 (73.7 KB) | WGT (8 KB) | A2P (2 KB) | SC/SH (256 B each)

typedef __bf16 bf16x8 __attribute__((ext_vector_type(8)));
typedef __bf16 bf16x4 __attribute__((ext_vector_type(4)));
typedef float  f32x4  __attribute__((ext_vector_type(4)));

#define Y_OFF   0
#define WC2_OFF 30720000
#define WGT_OFF 30793728
#define A2P_OFF 30801920
#define SC_OFF  30803968
#define SH_OFF  30804224

__global__ __launch_bounds__(256) void prep_kernel(
    const float* __restrict__ adj, const float* __restrict__ gcn_w,
    const float* __restrict__ conv_w, const float* __restrict__ conv_b,
    const float* __restrict__ bn_g, const float* __restrict__ bn_b,
    const float* __restrict__ bn_m, const float* __restrict__ bn_v,
    __bf16* __restrict__ wc2, __bf16* __restrict__ wgt,
    __bf16* __restrict__ a2p, float* __restrict__ scale, float* __restrict__ shift) {
  int tid = threadIdx.x;
  // conv weights -> fragment layout: wc2[((kk*4+quad)*64 + c)*8 + j] = w[c][ci][kt],
  // kap = (kk*4+quad)*8 + j = kt*64 + ci (kt-major K index).
  for (int e = blockIdx.x * 256 + tid; e < 36864; e += gridDim.x * 256) {
    int j = e & 7, t1 = e >> 3, c = t1 & 63, g = t1 >> 6;
    int kap = g * 8 + j, kt = kap >> 6, ci = kap & 63;
    wc2[e] = (__bf16)conv_w[(c * 64 + ci) * 9 + kt];
  }
  if (blockIdx.x == 0) {
    for (int e = tid; e < 4096; e += 256) {           // wgt[c][k] = gcn_w[k][c]
      int c = e >> 6, k = e & 63;
      wgt[e] = (__bf16)gcn_w[k * 64 + c];
    }
  } else if (blockIdx.x == 1) {
    for (int e = tid; e < 1024; e += 256) {           // A'' 32x32 zero-padded
      int v = e >> 5, u = e & 31;
      float val = 0.f;
      if (v < 25 && u < 25) {
        float dv = 0.f, du = 0.f;
        for (int t = 0; t < 25; ++t) { dv += adj[v * 25 + t]; du += adj[u * 25 + t]; }
        val = rsqrtf(dv) * adj[v * 25 + u] * rsqrtf(du);
      }
      a2p[e] = (__bf16)val;
    }
  } else if (blockIdx.x == 2) {
    if (tid < 64) {
      float sc = bn_g[tid] * rsqrtf(bn_v[tid] + 1e-5f);
      scale[tid] = sc;
      shift[tid] = (conv_b[tid] - bn_m[tid]) * sc + bn_b[tid];
    }
  }
}

// GCN v5: 1-wave blocks (9600), barrier-free, 9.2 KB LDS/wave. Weight fragments in
// registers (L2-hot global loads). X1T = Wg^T . h^T, LDS round-trip (x1t stride 40),
// yT = X1T . A''^T, ReLU+bias, ystage (reuse hb) -> coalesced y[nm][v][t][c] stores.
__global__ __launch_bounds__(64) void gcn_kernel(
    const float* __restrict__ h, const __bf16* __restrict__ wgt_g,
    const __bf16* __restrict__ a2p_g, const float* __restrict__ gcn_b,
    __bf16* __restrict__ y) {
  __shared__ __align__(16) __bf16 hb[2048];           // [u=32][k=64], chunk^(u&7) swizzle
  __shared__ __align__(16) __bf16 x1t[64 * 40];       // [c=64][u] stride 40 (bank rot 20)
  int lane = threadIdx.x;
  int l15 = lane & 15, quad = lane >> 4;
  int skel = blockIdx.x;                              // 9600 blocks
  int nm = skel / 300, tloc = skel - nm * 300;

  // weight fragments from global (same addresses every wave -> L2-hot)
  bf16x8 awg[4][2];
  for (int mt = 0; mt < 4; ++mt)
    for (int kk = 0; kk < 2; ++kk)
      awg[mt][kk] = *(const bf16x8*)&wgt_g[(mt * 16 + l15) * 64 + kk * 32 + quad * 8];
  bf16x8 ba[2];
  for (int nt = 0; nt < 2; ++nt)
    ba[nt] = *(const bf16x8*)&a2p_g[(nt * 16 + l15) * 32 + quad * 8];

  // stage h rows 0..24 (fp32 -> bf16, swizzled), zero rows 25..31
  if (lane < 56) *(uint4*)&hb[1600 + lane * 8] = (uint4){0u, 0u, 0u, 0u};
  for (int it = 0; it < 7; ++it) {
    int u = it * 4 + quad;
    if (u < 25) {
      float4 hv = *(const float4*)&h[(skel * 25 + u) * 64 + l15 * 4];
      bf16x4 b4; b4[0] = (__bf16)hv.x; b4[1] = (__bf16)hv.y; b4[2] = (__bf16)hv.z; b4[3] = (__bf16)hv.w;
      int ch = l15 >> 1;
      *(bf16x4*)&hb[u * 64 + (((ch ^ (u & 7)) * 8) | ((l15 & 1) * 4))] = b4;
    }
  }
  // GEMM1: M=c(64), N=u(32 pad), K=64
  for (int mt = 0; mt < 4; ++mt)
    for (int nt = 0; nt < 2; ++nt) {
      f32x4 acc = {0.f, 0.f, 0.f, 0.f};
      int u = nt * 16 + l15;
      for (int kk = 0; kk < 2; ++kk) {
        bf16x8 b = *(const bf16x8*)&hb[u * 64 + (((kk * 4 + quad) ^ (u & 7)) * 8)];
        acc = __builtin_amdgcn_mfma_f32_16x16x32_bf16(awg[mt][kk], b, acc, 0, 0, 0);
      }
      int c0 = mt * 16 + quad * 4;
      for (int r = 0; r < 4; ++r) x1t[(c0 + r) * 40 + u] = (__bf16)acc[r];
    }
  // GEMM2: M=c(64), N=v(32 pad), K=u(32 pad); epilogue -> ystage (reuse hb, swizzled)
  for (int mt = 0; mt < 4; ++mt)
    for (int nt = 0; nt < 2; ++nt) {
      f32x4 acc = {0.f, 0.f, 0.f, 0.f};
      bf16x8 a = *(const bf16x8*)&x1t[(mt * 16 + l15) * 40 + quad * 8];
      acc = __builtin_amdgcn_mfma_f32_16x16x32_bf16(a, ba[nt], acc, 0, 0, 0);
      int v = nt * 16 + l15, c0 = mt * 16 + quad * 4;
      if (v < 25) {
        float4 bias = *(const float4*)&gcn_b[c0];
        bf16x4 o;
        o[0] = (__bf16)fmaxf(acc[0] + bias.x, 0.f);
        o[1] = (__bf16)fmaxf(acc[1] + bias.y, 0.f);
        o[2] = (__bf16)fmaxf(acc[2] + bias.z, 0.f);
        o[3] = (__bf16)fmaxf(acc[3] + bias.w, 0.f);
        int ch = (c0 >> 3) ^ (v & 7);
        *(bf16x4*)&hb[v * 64 + ((ch * 8) | (c0 & 7))] = o;
      }
    }
  // coalesced store: y[((nm*25+v)*300 + tloc)*64 + c], 25 rows x 128 B
  for (int e = lane; e < 200; e += 64) {
    int v = e >> 3, ch = e & 7;
    uint4 val = *(const uint4*)&hb[v * 64 + ((ch ^ (v & 7)) * 8)];
    *(uint4*)&y[((nm * 25 + v) * 300 + tloc) * 64 + ch * 8] = val;
  }
}

// Conv v5: 4-wave blocks, shared 72x64 swizzled y tile, c-split: wave w owns
// c [w*16, w*16+16) x 64 t. Per kk: 1 A-frag (global, L2-hot) + 4 B-frags (LDS),
// 4 MFMAs. Epilogue: BN-fold + ReLU + fp32 residual.
__global__ __launch_bounds__(256, 8) void conv_kernel(
    const __bf16* __restrict__ y, const __bf16* __restrict__ wc2,
    const float* __restrict__ scale, const float* __restrict__ shift,
    const float* __restrict__ h, float* __restrict__ out) {
  __shared__ __align__(16) __bf16 my[72 * 64];        // 72 rows x 64c, XOR-swizzled
  int tid = threadIdx.x, w = tid >> 6, lane = tid & 63;
  int l15 = lane & 15, quad = lane >> 4;
  int ti = blockIdx.x, vv = blockIdx.y, nm = blockIdx.z;
  int t0 = (ti < 4) ? ti * 64 : 236;                  // last tile overlaps 20 rows (benign)

  { // cooperative stage: 72 rows x 128 B from y[nm][vv][t0-4 .. t0+67][:]
    const __bf16* ybase = &y[((nm * 25 + vv) * 300) * 64];
    uint4 stg[3];
    for (int it = 0; it < 3; ++it) {
      int idx = it * 256 + tid;
      uint4 val = {0u, 0u, 0u, 0u};
      if (idx < 576) {
        int r = idx >> 3, ch = idx & 7, tg = t0 - 4 + r;
        if (tg >= 0 && tg < 300) val = *(const uint4*)&ybase[tg * 64 + ch * 8];
      }
      stg[it] = val;
    }
    for (int it = 0; it < 3; ++it) {
      int idx = it * 256 + tid;
      if (idx < 576) {
        int r = idx >> 3, ch = idx & 7;
        *(uint4*)&my[r * 64 + ((ch ^ (r & 7)) * 8)] = stg[it];
      }
    }
  }
  __syncthreads();

  f32x4 acc[4];
  for (int n = 0; n < 4; ++n) acc[n] = (f32x4){0.f, 0.f, 0.f, 0.f};

  bf16x8 a0, a1;
#define LOADA(dst, kk_) dst = *(const bf16x8*)&wc2[((((kk_) * 4 + quad) * 64) + w * 16 + l15) * 8];
#define COMPUTE(kk_, areg) { int kt = (kk_) >> 1, chb = ((kk_) & 1) * 4 + quad; \
    for (int n = 0; n < 4; ++n) { \
      int row = n * 16 + l15 + kt; \
      bf16x8 b = *(const bf16x8*)&my[row * 64 + ((chb ^ (row & 7)) * 8)]; \
      acc[n] = __builtin_amdgcn_mfma_f32_16x16x32_bf16(areg, b, acc[n], 0, 0, 0); \
    } }
  LOADA(a0, 0)
  for (int kk = 0; kk < 18; kk += 2) {
    LOADA(a1, kk + 1)
    COMPUTE(kk, a0)
    if (kk + 2 < 18) LOADA(a0, kk + 2)
    COMPUTE(kk + 1, a1)
  }
#undef LOADA
#undef COMPUTE

  int c0 = w * 16 + quad * 4;
  float4 sc = *(const float4*)&scale[c0];
  float4 sh = *(const float4*)&shift[c0];
  for (int n = 0; n < 4; ++n) {
    int tt = t0 + n * 16 + l15;                       // always < 300 by tile choice
    int idx = ((nm * 300 + tt) * 25 + vv) * 64 + c0;
    float4 hr = *(const float4*)&h[idx];
    float4 o;
    o.x = fmaxf(acc[n][0] * sc.x + sh.x, 0.f) + hr.x;
    o.y = fmaxf(acc[n][1] * sc.y + sh.y, 0.f) + hr.y;
    o.z = fmaxf(acc[n][2] * sc.z + sh.z, 0.f) + hr.z;
    o.w = fmaxf(acc[n][3] * sc.w + sh.w, 0.f) + hr.w;
    *(float4*)&out[idx] = o;
  }
}

extern "C" void kernel_launch(void* const* d_in, const int* in_sizes, int n_in,
                              void* d_out, int out_size, void* d_ws, size_t ws_size,
                              hipStream_t stream) {
  const float* h      = (const float*)d_in[0];
  const float* adj    = (const float*)d_in[1];
  const float* gcn_w  = (const float*)d_in[2];
  const float* gcn_b  = (const float*)d_in[3];
  const float* conv_w = (const float*)d_in[4];
  const float* conv_b = (const float*)d_in[5];
  const float* bn_g   = (const float*)d_in[6];
  const float* bn_b   = (const float*)d_in[7];
  const float* bn_m   = (const float*)d_in[8];
  const float* bn_v   = (const float*)d_in[9];
  float* out = (float*)d_out;
  char* ws = (char*)d_ws;

  __bf16* y_ws   = (__bf16*)(ws + Y_OFF);
  __bf16* wc2    = (__bf16*)(ws + WC2_OFF);
  __bf16* wgt    = (__bf16*)(ws + WGT_OFF);
  __bf16* a2p    = (__bf16*)(ws + A2P_OFF);
  float*  scale  = (float*)(ws + SC_OFF);
  float*  shift  = (float*)(ws + SH_OFF);

  prep_kernel<<<64, 256, 0, stream>>>(adj, gcn_w, conv_w, conv_b, bn_g, bn_b, bn_m, bn_v,
                                      wc2, wgt, a2p, scale, shift);
  gcn_kernel<<<9600, 64, 0, stream>>>(h, wgt, a2p, gcn_b, y_ws);
  conv_kernel<<<dim3(5, 25, 32), 256, 0, stream>>>(y_ws, wc2, scale, shift, h, out);
}